// Round 1
// baseline (84.027 us; speedup 1.0000x reference)
//
#include <hip/hip_runtime.h>
#include <hip/hip_bf16.h>

// TripletLoss: B=4096, D=1024.
// out[0] = loss scalar, out[1..] = distances (4096x4096 f32, row-major).
// ws layout: t_bf16 [B*D], g_bf16 [B*D] (ushort), perrow [B] (float).

typedef __bf16 bf16x8 __attribute__((ext_vector_type(8)));
typedef float  f32x4  __attribute__((ext_vector_type(4)));

__device__ __forceinline__ void gload16(const void* g, void* l) {
  __builtin_amdgcn_global_load_lds(
      (__attribute__((address_space(1))) void*)(g),
      (__attribute__((address_space(3))) void*)(l), 16, 0, 0);
}

__device__ __forceinline__ ushort f2bf(float x) {
  __hip_bfloat16 h = __float2bfloat16(x);
  return *reinterpret_cast<ushort*>(&h);
}

// ---------------------------------------------------------------- normalize
__global__ __launch_bounds__(256) void k_normalize(
    const float* __restrict__ t, const float* __restrict__ g,
    ushort* __restrict__ tb, ushort* __restrict__ gb, int D) {
  const int row = blockIdx.x;
  const float* src = (blockIdx.y == 0 ? t : g) + (size_t)row * D;
  ushort*     dst  = (blockIdx.y == 0 ? tb : gb) + (size_t)row * D;
  const int nvec = D >> 2;

  float ss = 0.f;
  for (int c = threadIdx.x; c < nvec; c += 256) {
    float4 v = ((const float4*)src)[c];
    ss += v.x * v.x + v.y * v.y + v.z * v.z + v.w * v.w;
  }
#pragma unroll
  for (int off = 32; off; off >>= 1) ss += __shfl_down(ss, off);
  __shared__ float red[4];
  if ((threadIdx.x & 63) == 0) red[threadIdx.x >> 6] = ss;
  __syncthreads();
  float rn = red[0] + red[1] + red[2] + red[3];
  rn = 1.0f / fmaxf(sqrtf(rn), 1e-12f);

  for (int c = threadIdx.x; c < nvec; c += 256) {
    float4 v = ((const float4*)src)[c];
    ushort4 o;
    o.x = f2bf(v.x * rn);
    o.y = f2bf(v.y * rn);
    o.z = f2bf(v.z * rn);
    o.w = f2bf(v.w * rn);
    ((ushort4*)dst)[c] = o;
  }
}

// ---------------------------------------------------------------- GEMM
// C[i][j] = 1 - dot(Tn[i,:], Gn[j,:])   (both row-major BxK, bf16)
// 128x128 tile, BK=64, 4 waves (2x2), each wave 64x64 = 4x4 16x16 frags.
// LDS: [128][64] bf16 per operand, XOR-swizzled: data (r,k) stored at
// byte r*128 + ((k*2) ^ ((r&7)<<4)).  global_load_lds writes linearly,
// so the SOURCE address is inverse-swizzled (same involution).
__global__ __launch_bounds__(256) void k_gemm_dist(
    const ushort* __restrict__ A, const ushort* __restrict__ Bm,
    float* __restrict__ Dout, int N, int K) {
  __shared__ __align__(16) ushort Atile[128 * 64];
  __shared__ __align__(16) ushort Btile[128 * 64];

  const int tid  = threadIdx.x;
  const int lane = tid & 63;
  const int w    = tid >> 6;
  const int rowBase = blockIdx.y * 128;
  const int colBase = blockIdx.x * 128;
  const int waveM = w >> 1, waveN = w & 1;

  f32x4 acc[4][4];
#pragma unroll
  for (int m = 0; m < 4; ++m)
#pragma unroll
    for (int n = 0; n < 4; ++n) acc[m][n] = (f32x4){0.f, 0.f, 0.f, 0.f};

  // staging geometry: per issue q, this thread fills LDS bytes
  // q*4096 + w*1024 + lane*16  ->  row r = q*32 + w*8 + lane/8,
  // storage col-bytes (lane&7)*16. Inverse-swizzled source column:
  const int rr   = w * 8 + (lane >> 3);              // r mod 32 (q*32 keeps r&7)
  const int scol = (((lane & 7) ^ (rr & 7)) << 3);   // bf16 elements
  const ushort* aSrc = A  + (size_t)(rowBase + rr) * K + scol;
  const ushort* bSrc = Bm + (size_t)(colBase + rr) * K + scol;
  ushort* aDst = Atile + w * 512 + lane * 8;         // ushort units
  ushort* bDst = Btile + w * 512 + lane * 8;

  for (int kt = 0; kt < K; kt += 64) {
#pragma unroll
    for (int q = 0; q < 4; ++q) {
      gload16(aSrc + (size_t)q * 32 * K + kt, aDst + q * 2048);
      gload16(bSrc + (size_t)q * 32 * K + kt, bDst + q * 2048);
    }
    __syncthreads();   // compiler drains vmcnt before barrier

#pragma unroll
    for (int ks = 0; ks < 2; ++ks) {
      bf16x8 af[4], bfr[4];
      const int kbyte = ks * 64 + ((lane >> 4) << 4);
#pragma unroll
      for (int m = 0; m < 4; ++m) {
        const int r = waveM * 64 + m * 16 + (lane & 15);
        const int off = r * 128 + (kbyte ^ ((r & 7) << 4));
        af[m] = *(const bf16x8*)((const char*)Atile + off);
      }
#pragma unroll
      for (int n = 0; n < 4; ++n) {
        const int r = waveN * 64 + n * 16 + (lane & 15);
        const int off = r * 128 + (kbyte ^ ((r & 7) << 4));
        bfr[n] = *(const bf16x8*)((const char*)Btile + off);
      }
#pragma unroll
      for (int m = 0; m < 4; ++m)
#pragma unroll
        for (int n = 0; n < 4; ++n)
          acc[m][n] = __builtin_amdgcn_mfma_f32_16x16x32_bf16(
              af[m], bfr[n], acc[m][n], 0, 0, 0);
    }
    __syncthreads();
  }

  // epilogue: distances = 1 - acc.  C/D: col = lane&15, row = (lane>>4)*4+reg
#pragma unroll
  for (int m = 0; m < 4; ++m) {
    const int gi0 = rowBase + waveM * 64 + m * 16 + ((lane >> 4) << 2);
#pragma unroll
    for (int n = 0; n < 4; ++n) {
      const int gj = colBase + waveN * 64 + n * 16 + (lane & 15);
#pragma unroll
      for (int r = 0; r < 4; ++r)
        Dout[(size_t)(gi0 + r) * N + gj] = 1.0f - acc[m][n][r];
    }
  }
}

// ---------------------------------------------------------------- row reduce
__global__ __launch_bounds__(256) void k_row_reduce(
    const float* __restrict__ Dm, const int* __restrict__ labels,
    float* __restrict__ perrow, int N) {
  const int i  = blockIdx.x;
  const int li = labels[i];
  const float* row = Dm + (size_t)i * N;

  float mn = 1e9f;
  for (int j = threadIdx.x; j < N; j += 256) {
    float d = row[j];
    mn = fminf(mn, (labels[j] != li) ? d : 1e9f);
  }
#pragma unroll
  for (int off = 32; off; off >>= 1) mn = fminf(mn, __shfl_down(mn, off));
  __shared__ float red[4];
  if ((threadIdx.x & 63) == 0) red[threadIdx.x >> 6] = mn;
  __syncthreads();
  if (threadIdx.x == 0) {
    const float hn  = fminf(fminf(red[0], red[1]), fminf(red[2], red[3]));
    const float pos = row[i];
    const float pr  = pos - hn + 1.0f;          // MARGIN = 1.0
    perrow[i] = pr > 0.f ? pr : 0.f;            // hn==1e9 rows -> 0 (has_neg)
  }
}

// ---------------------------------------------------------------- final sum
__global__ __launch_bounds__(256) void k_final(
    const float* __restrict__ perrow, float* __restrict__ out, int N) {
  float s = 0.f;
  for (int j = threadIdx.x; j < N; j += 256) s += perrow[j];
#pragma unroll
  for (int off = 32; off; off >>= 1) s += __shfl_down(s, off);
  __shared__ float red[4];
  if ((threadIdx.x & 63) == 0) red[threadIdx.x >> 6] = s;
  __syncthreads();
  if (threadIdx.x == 0) out[0] = (red[0] + red[1] + red[2] + red[3]) / (float)N;
}

extern "C" void kernel_launch(void* const* d_in, const int* in_sizes, int n_in,
                              void* d_out, int out_size, void* d_ws, size_t ws_size,
                              hipStream_t stream) {
  const float* t      = (const float*)d_in[0];
  const float* g      = (const float*)d_in[1];
  const int*   labels = (const int*)d_in[2];
  const int Bn = in_sizes[2];          // 4096
  const int D  = in_sizes[0] / Bn;     // 1024

  float* out  = (float*)d_out;
  float* dist = out + 1;

  ushort* tb     = (ushort*)d_ws;
  ushort* gb     = tb + (size_t)Bn * D;
  float*  perrow = (float*)(gb + (size_t)Bn * D);

  k_normalize<<<dim3(Bn, 2), 256, 0, stream>>>(t, g, tb, gb, D);
  k_gemm_dist<<<dim3(Bn / 128, Bn / 128), 256, 0, stream>>>(tb, gb, dist, Bn, D);
  k_row_reduce<<<Bn, 256, 0, stream>>>(dist, labels, perrow, Bn);
  k_final<<<1, 256, 0, stream>>>(perrow, out, Bn);
}

// Round 2
// 67.575 us; speedup vs baseline: 1.2435x; 1.2435x over previous
//
#include <hip/hip_runtime.h>
#include <hip/hip_bf16.h>

// TripletLoss: B=4096, D=1024.
// out[0] = loss scalar, out[1..] = distances (4096x4096 f32, row-major).
// ws: t_bf16 [B*D] ushort, g_bf16 [B*D] ushort, hn_key [B] int, pos [B] float.

typedef __bf16 bf16x8 __attribute__((ext_vector_type(8)));
typedef float  f32x4  __attribute__((ext_vector_type(4)));

__device__ __forceinline__ void gload16(const void* g, void* l) {
  __builtin_amdgcn_global_load_lds(
      (__attribute__((address_space(1))) void*)(g),
      (__attribute__((address_space(3))) void*)(l), 16, 0, 0);
}

__device__ __forceinline__ ushort f2bf(float x) {
  __hip_bfloat16 h = __float2bfloat16(x);
  return *reinterpret_cast<ushort*>(&h);
}

// order-preserving float->int key (works for negatives too)
__device__ __forceinline__ int fkey(float x) {
  int u = __float_as_int(x);
  return u >= 0 ? u : (u ^ 0x7fffffff);
}
__device__ __forceinline__ float funkey(int k) {
  return __int_as_float(k >= 0 ? k : (k ^ 0x7fffffff));
}

// ---------------------------------------------------------------- normalize
// one float4 per thread (D=1024, 256 threads), single pass; also inits hn_key
__global__ __launch_bounds__(256) void k_normalize(
    const float* __restrict__ t, const float* __restrict__ g,
    ushort* __restrict__ tb, ushort* __restrict__ gb,
    int* __restrict__ hn_key, int D) {
  const int row = blockIdx.x;
  const float* src = (blockIdx.y ? g : t) + (size_t)row * D;
  ushort*     dst  = (blockIdx.y ? gb : tb) + (size_t)row * D;

  float4 v = ((const float4*)src)[threadIdx.x];
  float ss = v.x * v.x + v.y * v.y + v.z * v.z + v.w * v.w;
#pragma unroll
  for (int off = 32; off; off >>= 1) ss += __shfl_down(ss, off);
  __shared__ float red[4];
  if ((threadIdx.x & 63) == 0) red[threadIdx.x >> 6] = ss;
  __syncthreads();
  float rn = red[0] + red[1] + red[2] + red[3];
  rn = 1.0f / fmaxf(sqrtf(rn), 1e-12f);

  ushort4 o;
  o.x = f2bf(v.x * rn); o.y = f2bf(v.y * rn);
  o.z = f2bf(v.z * rn); o.w = f2bf(v.w * rn);
  ((ushort4*)dst)[threadIdx.x] = o;

  if (blockIdx.y == 0 && threadIdx.x == 0) hn_key[row] = __float_as_int(1e9f);
}

// ---------------------------------------------------------------- GEMM fused
// 256x256 tile, BK=64, 512 thr = 8 waves (2M x 4N), per-wave 128x64 (8x4 frags).
// Double-buffered LDS, 4 phases/tile (8 per buffer pair), raw s_barrier per
// phase (no vmcnt drain), stage spread 2 issues/phase, vmcnt(0) publish once
// per tile. LDS swizzle: data (r,k) at byte r*128 + (2k ^ ((r&7)<<4)); linear
// gload_lds dest + inverse-swizzled global source (verified conflict-free).
// Epilogue: distances store + fused per-row hard-negative min + diagonal pos.
__global__ __launch_bounds__(512, 2) void k_gemm_fused(
    const ushort* __restrict__ A, const ushort* __restrict__ Bm,
    const int* __restrict__ labels, float* __restrict__ Dout,
    int* __restrict__ hn_key, float* __restrict__ pos, int N, int K) {
  __shared__ __align__(16) ushort Atile[2][256 * 64];
  __shared__ __align__(16) ushort Btile[2][256 * 64];
  __shared__ int labR[256], labC[256], hnmin[256];

  const int tid  = threadIdx.x;
  const int lane = tid & 63;
  const int w    = tid >> 6;
  const int waveM = w >> 2, waveN = w & 3;

  // T1: XCD-aware bijective swizzle (nb*nb % 8 == 0 for B=4096)
  const int nb  = N >> 8;               // 16
  const int cpx = (nb * nb) >> 3;       // 32
  const int bid = blockIdx.x;
  const int swz = (bid & 7) * cpx + (bid >> 3);
  const int rowBase = (swz / nb) * 256;
  const int colBase = (swz % nb) * 256;

  // staging geometry (round q: row = q*64 + tid/8, inverse-swizzled src col)
  const int rr   = tid >> 3;                       // 0..63
  const int scol = ((tid & 7) ^ (rr & 7)) << 3;    // bf16 elements
  const ushort* aS = A  + (size_t)(rowBase + rr) * K + scol;
  const ushort* bS = Bm + (size_t)(colBase + rr) * K + scol;
  const int ldsDst = tid * 8;                      // ushort units within round

  // fragment read offsets (bytes within a buffer)
  const int sw  = (lane & 7) << 4;
  const int khi = ((lane >> 4) << 4);
  const int kx0 = khi ^ sw;
  const int kx1 = (64 + khi) ^ sw;
  const int aOffBase = (waveM * 128 + (lane & 15)) * 128;
  const int bOffBase = (waveN * 64  + (lane & 15)) * 128;

  // prologue: stage tile 0 into buf0; labels + hnmin init; full syncthreads
#pragma unroll
  for (int q = 0; q < 4; ++q) {
    gload16(aS + (size_t)q * 64 * K, &Atile[0][q * 4096 + ldsDst]);
    gload16(bS + (size_t)q * 64 * K, &Btile[0][q * 4096 + ldsDst]);
  }
  if (tid < 256) {
    labR[tid]  = labels[rowBase + tid];
    labC[tid]  = labels[colBase + tid];
    hnmin[tid] = __float_as_int(1e9f);
  }
  __syncthreads();   // drains vmcnt(0): tile 0 published

  f32x4 acc[8][4];
#pragma unroll
  for (int m = 0; m < 8; ++m)
#pragma unroll
    for (int n = 0; n < 4; ++n) acc[m][n] = (f32x4){0.f, 0.f, 0.f, 0.f};

  const int NT = K >> 6;   // 16
  for (int t = 0; t < NT; ++t) {
    const int cur = t & 1;
    const char* Ab = (const char*)&Atile[cur][0];
    const char* Bb = (const char*)&Btile[cur][0];
    const bool pre = (t + 1 < NT);

#pragma unroll
    for (int q = 0; q < 4; ++q) {       // phase: quadrant (m-half, n-half)
      const int mh = q >> 1, nh = q & 1;
      bf16x8 af[4][2], bf[2][2];
#pragma unroll
      for (int mq = 0; mq < 4; ++mq) {
        const int ro = aOffBase + (mh * 4 + mq) * 2048;
        af[mq][0] = *(const bf16x8*)(Ab + ro + kx0);
        af[mq][1] = *(const bf16x8*)(Ab + ro + kx1);
      }
#pragma unroll
      for (int nq = 0; nq < 2; ++nq) {
        const int ro = bOffBase + (nh * 2 + nq) * 2048;
        bf[nq][0] = *(const bf16x8*)(Bb + ro + kx0);
        bf[nq][1] = *(const bf16x8*)(Bb + ro + kx1);
      }
      if (pre) {   // stage 2 issues of tile t+1 into the other buffer
        gload16(aS + (size_t)q * 64 * K + (size_t)(t + 1) * 64,
                &Atile[cur ^ 1][q * 4096 + ldsDst]);
        gload16(bS + (size_t)q * 64 * K + (size_t)(t + 1) * 64,
                &Btile[cur ^ 1][q * 4096 + ldsDst]);
      }
      __builtin_amdgcn_s_barrier();     // raw: no vmcnt drain
      __builtin_amdgcn_s_setprio(1);
#pragma unroll
      for (int ks = 0; ks < 2; ++ks)
#pragma unroll
        for (int mq = 0; mq < 4; ++mq)
#pragma unroll
          for (int nq = 0; nq < 2; ++nq)
            acc[mh * 4 + mq][nh * 2 + nq] =
                __builtin_amdgcn_mfma_f32_16x16x32_bf16(
                    af[mq][ks], bf[nq][ks], acc[mh * 4 + mq][nh * 2 + nq],
                    0, 0, 0);
      __builtin_amdgcn_s_setprio(0);
      if (q < 3) __builtin_amdgcn_s_barrier();
    }

    if (pre) {
      asm volatile("s_waitcnt vmcnt(0)" ::: "memory");  // publish tile t+1
      __builtin_amdgcn_s_barrier();
      asm volatile("" ::: "memory");    // keep next-tile ds_reads below barrier
    }
  }

  // ---------------- fused epilogue: store distances + per-row hard-neg min
  const int ci = lane & 15;
  const int r4 = (lane >> 4) << 2;
  const bool diagBlk = (rowBase == colBase);
#pragma unroll
  for (int m = 0; m < 8; ++m) {
    const int gilB = waveM * 128 + m * 16 + r4;
#pragma unroll
    for (int r = 0; r < 4; ++r) {
      const int gil = gilB + r;
      const int li  = labR[gil];
      const size_t gi = (size_t)(rowBase + gil);
      float mn = 1e9f;
#pragma unroll
      for (int n = 0; n < 4; ++n) {
        const int gjl = waveN * 64 + n * 16 + ci;
        const float d = 1.0f - acc[m][n][r];
        Dout[gi * N + (colBase + gjl)] = d;
        if (labC[gjl] != li) mn = fminf(mn, d);
        if (diagBlk && gil == gjl) pos[gi] = d;
      }
#pragma unroll
      for (int off = 1; off < 16; off <<= 1) mn = fminf(mn, __shfl_xor(mn, off));
      if (ci == 0) atomicMin(&hnmin[gil], fkey(mn));
    }
  }
  __syncthreads();
  if (tid < 256) atomicMin(&hn_key[rowBase + tid], hnmin[tid]);
}

// ---------------------------------------------------------------- final sum
__global__ __launch_bounds__(256) void k_final(
    const int* __restrict__ hn_key, const float* __restrict__ pos,
    float* __restrict__ out, int N) {
  float s = 0.f;
  for (int i = threadIdx.x; i < N; i += 256) {
    const float hn = funkey(hn_key[i]);
    const float pr = pos[i] - hn + 1.0f;   // MARGIN = 1.0
    s += pr > 0.f ? pr : 0.f;              // hn==1e9 rows (no negatives) -> 0
  }
#pragma unroll
  for (int off = 32; off; off >>= 1) s += __shfl_down(s, off);
  __shared__ float red[4];
  if ((threadIdx.x & 63) == 0) red[threadIdx.x >> 6] = s;
  __syncthreads();
  if (threadIdx.x == 0) out[0] = (red[0] + red[1] + red[2] + red[3]) / (float)N;
}

extern "C" void kernel_launch(void* const* d_in, const int* in_sizes, int n_in,
                              void* d_out, int out_size, void* d_ws, size_t ws_size,
                              hipStream_t stream) {
  const float* t      = (const float*)d_in[0];
  const float* g      = (const float*)d_in[1];
  const int*   labels = (const int*)d_in[2];
  const int Bn = in_sizes[2];          // 4096
  const int D  = in_sizes[0] / Bn;     // 1024

  float* out  = (float*)d_out;
  float* dist = out + 1;

  ushort* tb     = (ushort*)d_ws;
  ushort* gb     = tb + (size_t)Bn * D;
  int*    hn_key = (int*)(gb + (size_t)Bn * D);
  float*  pos    = (float*)(hn_key + Bn);

  k_normalize<<<dim3(Bn, 2), 256, 0, stream>>>(t, g, tb, gb, hn_key, D);
  const int nb = Bn / 256;
  k_gemm_fused<<<dim3(nb * nb), 512, 0, stream>>>(tb, gb, labels, dist,
                                                  hn_key, pos, Bn, D);
  k_final<<<1, 256, 0, stream>>>(hn_key, pos, out, Bn);
}

// Round 3
// 62.423 us; speedup vs baseline: 1.3461x; 1.0825x over previous
//
#include <hip/hip_runtime.h>
#include <hip/hip_bf16.h>

// TripletLoss: B=4096, D=1024.
// out[0] = loss scalar, out[1..] = distances (4096x4096 f32, row-major).
// ws: t_bf16 [B*D] ushort, g_bf16 [B*D] ushort, hn_key [B] int, pos [B] float.

typedef __bf16 bf16x8 __attribute__((ext_vector_type(8)));
typedef float  f32x4  __attribute__((ext_vector_type(4)));

__device__ __forceinline__ void gload16(const void* g, void* l) {
  __builtin_amdgcn_global_load_lds(
      (__attribute__((address_space(1))) void*)(g),
      (__attribute__((address_space(3))) void*)(l), 16, 0, 0);
}

__device__ __forceinline__ ushort f2bf(float x) {
  __hip_bfloat16 h = __float2bfloat16(x);
  return *reinterpret_cast<ushort*>(&h);
}

// order-preserving float->int key (works for negatives too)
__device__ __forceinline__ int fkey(float x) {
  int u = __float_as_int(x);
  return u >= 0 ? u : (u ^ 0x7fffffff);
}
__device__ __forceinline__ float funkey(int k) {
  return __int_as_float(k >= 0 ? k : (k ^ 0x7fffffff));
}

// ---------------------------------------------------------------- normalize
__global__ __launch_bounds__(256) void k_normalize(
    const float* __restrict__ t, const float* __restrict__ g,
    ushort* __restrict__ tb, ushort* __restrict__ gb,
    int* __restrict__ hn_key, int D) {
  const int row = blockIdx.x;
  const float* src = (blockIdx.y ? g : t) + (size_t)row * D;
  ushort*     dst  = (blockIdx.y ? gb : tb) + (size_t)row * D;

  float4 v = ((const float4*)src)[threadIdx.x];
  float ss = v.x * v.x + v.y * v.y + v.z * v.z + v.w * v.w;
#pragma unroll
  for (int off = 32; off; off >>= 1) ss += __shfl_down(ss, off);
  __shared__ float red[4];
  if ((threadIdx.x & 63) == 0) red[threadIdx.x >> 6] = ss;
  __syncthreads();
  float rn = red[0] + red[1] + red[2] + red[3];
  rn = 1.0f / fmaxf(sqrtf(rn), 1e-12f);

  ushort4 o;
  o.x = f2bf(v.x * rn); o.y = f2bf(v.y * rn);
  o.z = f2bf(v.z * rn); o.w = f2bf(v.w * rn);
  ((ushort4*)dst)[threadIdx.x] = o;

  if (blockIdx.y == 0 && threadIdx.x == 0) hn_key[row] = __float_as_int(1e9f);
}

// ---------------------------------------------------------------- GEMM fused
// 256x256 tile, BK=64, 512 thr = 8 waves (2M x 4N), per-wave 128x64.
// 4 phases/K-tile, NO duplicate LDS reads (24 ds_read_b128/tile/wave):
//   P0: read A-lo(8)+B-lo(4), stage 4 -> MFMA quad(0,0)
//   P1: read B-hi(4),         stage 4 -> MFMA quad(0,1)
//   P2: read A-hi(8, reuse regs)      -> MFMA quad(1,1)
//   P3: (no reads)                    -> MFMA quad(1,0); vmcnt(0); barrier
// All 8 prefetch issues happen in P0+P1 so the tile-boundary vmcnt(0) has
// >=2 phases of cover. LDS swizzle: (r,k) at byte r*128 + (2k ^ ((r&7)<<4));
// linear gload_lds dest + inverse-swizzled global source.
__global__ __launch_bounds__(512, 2) void k_gemm_fused(
    const ushort* __restrict__ A, const ushort* __restrict__ Bm,
    const int* __restrict__ labels, float* __restrict__ Dout,
    int* __restrict__ hn_key, float* __restrict__ pos, int N, int K) {
  __shared__ __align__(16) ushort Atile[2][256 * 64];
  __shared__ __align__(16) ushort Btile[2][256 * 64];
  __shared__ int labR[256], labC[256], hnmin[256];

  const int tid  = threadIdx.x;
  const int lane = tid & 63;
  const int w    = tid >> 6;
  const int waveM = w >> 2, waveN = w & 3;

  // T1: XCD-aware bijective swizzle (nb*nb % 8 == 0 for B=4096)
  const int nb  = N >> 8;               // 16
  const int cpx = (nb * nb) >> 3;       // 32
  const int bid = blockIdx.x;
  const int swz = (bid & 7) * cpx + (bid >> 3);
  const int rowBase = (swz / nb) * 256;
  const int colBase = (swz % nb) * 256;

  // staging geometry (round q: row = q*64 + tid/8, inverse-swizzled src col)
  const int rr   = tid >> 3;                       // 0..63
  const int scol = ((tid & 7) ^ (rr & 7)) << 3;    // bf16 elements
  const ushort* aS = A  + (size_t)(rowBase + rr) * K + scol;
  const ushort* bS = Bm + (size_t)(colBase + rr) * K + scol;
  const int ldsDst = tid * 8;                      // ushort units within round

  // fragment read offsets (bytes within a buffer)
  const int sw  = (lane & 7) << 4;
  const int khi = ((lane >> 4) << 4);
  const int kx0 = khi ^ sw;
  const int kx1 = (64 + khi) ^ sw;
  const int aOffBase = (waveM * 128 + (lane & 15)) * 128;
  const int bOffBase = (waveN * 64  + (lane & 15)) * 128;

  // prologue: stage tile 0 into buf0; labels + hnmin init
#pragma unroll
  for (int q = 0; q < 4; ++q) {
    gload16(aS + (size_t)q * 64 * K, &Atile[0][q * 4096 + ldsDst]);
    gload16(bS + (size_t)q * 64 * K, &Btile[0][q * 4096 + ldsDst]);
  }
  if (tid < 256) {
    labR[tid]  = labels[rowBase + tid];
    labC[tid]  = labels[colBase + tid];
    hnmin[tid] = __float_as_int(1e9f);
  }
  __syncthreads();   // drains vmcnt(0): tile 0 published

  f32x4 acc[8][4];
#pragma unroll
  for (int m = 0; m < 8; ++m)
#pragma unroll
    for (int n = 0; n < 4; ++n) acc[m][n] = (f32x4){0.f, 0.f, 0.f, 0.f};

  const int NT = K >> 6;   // 16
  for (int t = 0; t < NT; ++t) {
    const int cur = t & 1;
    const char* Ab = (const char*)&Atile[cur][0];
    const char* Bb = (const char*)&Btile[cur][0];
    ushort* An = &Atile[cur ^ 1][0];
    ushort* Bn = &Btile[cur ^ 1][0];
    const bool pre = (t + 1 < NT);
    const size_t koff = (size_t)(t + 1) * 64;

    bf16x8 af[4][2], bfl[2][2], bfh[2][2];

    // ---- P0: read A-lo + B-lo; stage rounds 0,1; MFMA quad (0,0)
#pragma unroll
    for (int mq = 0; mq < 4; ++mq) {
      const int ro = aOffBase + mq * 2048;
      af[mq][0] = *(const bf16x8*)(Ab + ro + kx0);
      af[mq][1] = *(const bf16x8*)(Ab + ro + kx1);
    }
#pragma unroll
    for (int nq = 0; nq < 2; ++nq) {
      const int ro = bOffBase + nq * 2048;
      bfl[nq][0] = *(const bf16x8*)(Bb + ro + kx0);
      bfl[nq][1] = *(const bf16x8*)(Bb + ro + kx1);
    }
    if (pre) {
      gload16(aS + koff,                  An + 0 * 4096 + ldsDst);
      gload16(bS + koff,                  Bn + 0 * 4096 + ldsDst);
      gload16(aS + (size_t)1 * 64 * K + koff, An + 1 * 4096 + ldsDst);
      gload16(bS + (size_t)1 * 64 * K + koff, Bn + 1 * 4096 + ldsDst);
    }
    __builtin_amdgcn_s_barrier();
    __builtin_amdgcn_s_setprio(1);
#pragma unroll
    for (int ks = 0; ks < 2; ++ks)
#pragma unroll
      for (int mq = 0; mq < 4; ++mq)
#pragma unroll
        for (int nq = 0; nq < 2; ++nq)
          acc[mq][nq] = __builtin_amdgcn_mfma_f32_16x16x32_bf16(
              af[mq][ks], bfl[nq][ks], acc[mq][nq], 0, 0, 0);
    __builtin_amdgcn_s_setprio(0);
    __builtin_amdgcn_s_barrier();

    // ---- P1: read B-hi; stage rounds 2,3; MFMA quad (0,1)
#pragma unroll
    for (int nq = 0; nq < 2; ++nq) {
      const int ro = bOffBase + (2 + nq) * 2048;
      bfh[nq][0] = *(const bf16x8*)(Bb + ro + kx0);
      bfh[nq][1] = *(const bf16x8*)(Bb + ro + kx1);
    }
    if (pre) {
      gload16(aS + (size_t)2 * 64 * K + koff, An + 2 * 4096 + ldsDst);
      gload16(bS + (size_t)2 * 64 * K + koff, Bn + 2 * 4096 + ldsDst);
      gload16(aS + (size_t)3 * 64 * K + koff, An + 3 * 4096 + ldsDst);
      gload16(bS + (size_t)3 * 64 * K + koff, Bn + 3 * 4096 + ldsDst);
    }
    __builtin_amdgcn_s_barrier();
    __builtin_amdgcn_s_setprio(1);
#pragma unroll
    for (int ks = 0; ks < 2; ++ks)
#pragma unroll
      for (int mq = 0; mq < 4; ++mq)
#pragma unroll
        for (int nq = 0; nq < 2; ++nq)
          acc[mq][2 + nq] = __builtin_amdgcn_mfma_f32_16x16x32_bf16(
              af[mq][ks], bfh[nq][ks], acc[mq][2 + nq], 0, 0, 0);
    __builtin_amdgcn_s_setprio(0);
    __builtin_amdgcn_s_barrier();

    // ---- P2: read A-hi (reuse af regs); MFMA quad (1,1)
#pragma unroll
    for (int mq = 0; mq < 4; ++mq) {
      const int ro = aOffBase + (4 + mq) * 2048;
      af[mq][0] = *(const bf16x8*)(Ab + ro + kx0);
      af[mq][1] = *(const bf16x8*)(Ab + ro + kx1);
    }
    __builtin_amdgcn_s_barrier();
    __builtin_amdgcn_s_setprio(1);
#pragma unroll
    for (int ks = 0; ks < 2; ++ks)
#pragma unroll
      for (int mq = 0; mq < 4; ++mq)
#pragma unroll
        for (int nq = 0; nq < 2; ++nq)
          acc[4 + mq][2 + nq] = __builtin_amdgcn_mfma_f32_16x16x32_bf16(
              af[mq][ks], bfh[nq][ks], acc[4 + mq][2 + nq], 0, 0, 0);
    __builtin_amdgcn_s_setprio(0);
    __builtin_amdgcn_s_barrier();

    // ---- P3: no reads; MFMA quad (1,0); publish next tile
    __builtin_amdgcn_s_setprio(1);
#pragma unroll
    for (int ks = 0; ks < 2; ++ks)
#pragma unroll
      for (int mq = 0; mq < 4; ++mq)
#pragma unroll
        for (int nq = 0; nq < 2; ++nq)
          acc[4 + mq][nq] = __builtin_amdgcn_mfma_f32_16x16x32_bf16(
              af[mq][ks], bfl[nq][ks], acc[4 + mq][nq], 0, 0, 0);
    __builtin_amdgcn_s_setprio(0);
    if (pre) {
      asm volatile("s_waitcnt vmcnt(0)" ::: "memory");  // own loads landed
      __builtin_amdgcn_s_barrier();                     // all waves' loads
      asm volatile("" ::: "memory");    // keep next-tile ds_reads below
    }
  }

  // ---------------- fused epilogue: store distances + per-row hard-neg min
  const int ci = lane & 15;
  const int r4 = (lane >> 4) << 2;
  const bool diagBlk = (rowBase == colBase);
#pragma unroll
  for (int m = 0; m < 8; ++m) {
    const int gilB = waveM * 128 + m * 16 + r4;
#pragma unroll
    for (int r = 0; r < 4; ++r) {
      const int gil = gilB + r;
      const int li  = labR[gil];
      const size_t gi = (size_t)(rowBase + gil);
      float mn = 1e9f;
#pragma unroll
      for (int n = 0; n < 4; ++n) {
        const int gjl = waveN * 64 + n * 16 + ci;
        const float d = 1.0f - acc[m][n][r];
        Dout[gi * N + (colBase + gjl)] = d;
        if (labC[gjl] != li) mn = fminf(mn, d);
        if (diagBlk && gil == gjl) pos[gi] = d;
      }
#pragma unroll
      for (int off = 1; off < 16; off <<= 1) mn = fminf(mn, __shfl_xor(mn, off));
      if (ci == 0) atomicMin(&hnmin[gil], fkey(mn));
    }
  }
  __syncthreads();
  if (tid < 256) atomicMin(&hn_key[rowBase + tid], hnmin[tid]);
}

// ---------------------------------------------------------------- final sum
__global__ __launch_bounds__(256) void k_final(
    const int* __restrict__ hn_key, const float* __restrict__ pos,
    float* __restrict__ out, int N) {
  float s = 0.f;
  for (int i = threadIdx.x; i < N; i += 256) {
    const float hn = funkey(hn_key[i]);
    const float pr = pos[i] - hn + 1.0f;   // MARGIN = 1.0
    s += pr > 0.f ? pr : 0.f;              // hn==1e9 rows (no negatives) -> 0
  }
#pragma unroll
  for (int off = 32; off; off >>= 1) s += __shfl_down(s, off);
  __shared__ float red[4];
  if ((threadIdx.x & 63) == 0) red[threadIdx.x >> 6] = s;
  __syncthreads();
  if (threadIdx.x == 0) out[0] = (red[0] + red[1] + red[2] + red[3]) / (float)N;
}

extern "C" void kernel_launch(void* const* d_in, const int* in_sizes, int n_in,
                              void* d_out, int out_size, void* d_ws, size_t ws_size,
                              hipStream_t stream) {
  const float* t      = (const float*)d_in[0];
  const float* g      = (const float*)d_in[1];
  const int*   labels = (const int*)d_in[2];
  const int Bn = in_sizes[2];          // 4096
  const int D  = in_sizes[0] / Bn;     // 1024

  float* out  = (float*)d_out;
  float* dist = out + 1;

  ushort* tb     = (ushort*)d_ws;
  ushort* gb     = tb + (size_t)Bn * D;
  int*    hn_key = (int*)(gb + (size_t)Bn * D);
  float*  pos    = (float*)(hn_key + Bn);

  k_normalize<<<dim3(Bn, 2), 256, 0, stream>>>(t, g, tb, gb, hn_key, D);
  const int nb = Bn / 256;
  k_gemm_fused<<<dim3(nb * nb), 512, 0, stream>>>(tb, gb, labels, dist,
                                                  hn_key, pos, Bn, D);
  k_final<<<1, 256, 0, stream>>>(hn_key, pos, out, Bn);
}